// Round 1
// baseline (115.613 us; speedup 1.0000x reference)
//
#include <hip/hip_runtime.h>
#include <math.h>

#define IMG_H 512
#define IMG_W 512
#define TW 64
#define TH 16
#define KR 5          // radius
#define KS 11         // taps
#define NTHREADS 256

struct W11 { float w[KS]; };

// Phase A+B fused SSIM tile kernel.
// Each block: one TW x TH output tile of one (n,c) plane.
__global__ __launch_bounds__(NTHREADS)
void ssim_tile_kernel(const float* __restrict__ img1, const float* __restrict__ img2,
                      float* __restrict__ bsums, W11 wt) {
    // vertical-conv staging: 5 fields, TH rows, TW+10 cols
    __shared__ float s[5][TH][TW + 2 * KR];
    __shared__ float red[NTHREADS];

    const int col0  = blockIdx.x * TW;
    const int row0  = blockIdx.y * TH;
    const int plane = blockIdx.z;
    const float* __restrict__ p1 = img1 + (size_t)plane * (IMG_H * IMG_W);
    const float* __restrict__ p2 = img2 + (size_t)plane * (IMG_H * IMG_W);
    const int tid = threadIdx.x;

    // ---- Phase A: vertical 11-tap conv from global -> LDS ----
    const int SW = TW + 2 * KR;  // 74
    for (int i = tid; i < TH * SW; i += NTHREADS) {
        const int r = i / SW;
        const int c = i - r * SW;
        const int gr = row0 + r;            // output row
        const int gc = col0 - KR + c;       // input col (may be in padding)
        float s1 = 0.f, s2 = 0.f, s11 = 0.f, s22 = 0.f, s12 = 0.f;
        if (gc >= 0 && gc < IMG_W) {
            const float* q1 = p1 + gc;
            const float* q2 = p2 + gc;
            if (gr >= KR && gr < IMG_H - KR) {
                // interior rows: no per-tap bound check
                #pragma unroll
                for (int k = 0; k < KS; ++k) {
                    const int rr = gr - KR + k;
                    const float a = q1[rr * IMG_W];
                    const float b = q2[rr * IMG_W];
                    const float wk = wt.w[k];
                    s1  = fmaf(wk, a, s1);
                    s2  = fmaf(wk, b, s2);
                    s11 = fmaf(wk * a, a, s11);
                    s22 = fmaf(wk * b, b, s22);
                    s12 = fmaf(wk * a, b, s12);
                }
            } else {
                #pragma unroll
                for (int k = 0; k < KS; ++k) {
                    const int rr = gr - KR + k;
                    if (rr >= 0 && rr < IMG_H) {
                        const float a = q1[rr * IMG_W];
                        const float b = q2[rr * IMG_W];
                        const float wk = wt.w[k];
                        s1  = fmaf(wk, a, s1);
                        s2  = fmaf(wk, b, s2);
                        s11 = fmaf(wk * a, a, s11);
                        s22 = fmaf(wk * b, b, s22);
                        s12 = fmaf(wk * a, b, s12);
                    }
                }
            }
        }
        s[0][r][c] = s1;
        s[1][r][c] = s2;
        s[2][r][c] = s11;
        s[3][r][c] = s22;
        s[4][r][c] = s12;
    }
    __syncthreads();

    // ---- Phase B: horizontal 11-tap conv from LDS + SSIM map + local sum ----
    const float C1 = 0.0001f;   // 0.01^2
    const float C2 = 0.0009f;   // 0.03^2
    float lsum = 0.f;
    for (int i = tid; i < TH * TW; i += NTHREADS) {
        const int r = i >> 6;    // / TW
        const int c = i & 63;    // % TW
        float m1 = 0.f, m2 = 0.f, m11 = 0.f, m22 = 0.f, m12 = 0.f;
        #pragma unroll
        for (int k = 0; k < KS; ++k) {
            const float wk = wt.w[k];
            m1  = fmaf(wk, s[0][r][c + k], m1);
            m2  = fmaf(wk, s[1][r][c + k], m2);
            m11 = fmaf(wk, s[2][r][c + k], m11);
            m22 = fmaf(wk, s[3][r][c + k], m22);
            m12 = fmaf(wk, s[4][r][c + k], m12);
        }
        const float mu1_sq  = m1 * m1;
        const float mu2_sq  = m2 * m2;
        const float mu1_mu2 = m1 * m2;
        const float sig1 = m11 - mu1_sq;
        const float sig2 = m22 - mu2_sq;
        const float sig12 = m12 - mu1_mu2;
        const float num = (2.f * mu1_mu2 + C1) * (2.f * sig12 + C2);
        const float den = (mu1_sq + mu2_sq + C1) * (sig1 + sig2 + C2);
        lsum += num / den;
    }

    // ---- block reduction ----
    red[tid] = lsum;
    __syncthreads();
    #pragma unroll
    for (int off = NTHREADS / 2; off > 0; off >>= 1) {
        if (tid < off) red[tid] += red[tid + off];
        __syncthreads();
    }
    if (tid == 0) {
        const int bid = (blockIdx.z * gridDim.y + blockIdx.y) * gridDim.x + blockIdx.x;
        bsums[bid] = red[0];
    }
}

// Final reduce in double (fp32 sequential sum of 1.26e7-magnitude total would
// exceed the 2.6e-4 threshold).
__global__ __launch_bounds__(NTHREADS)
void ssim_reduce_kernel(const float* __restrict__ bsums, int n,
                        float* __restrict__ out, double inv_count) {
    __shared__ double red[NTHREADS];
    double acc = 0.0;
    for (int i = threadIdx.x; i < n; i += NTHREADS) acc += (double)bsums[i];
    red[threadIdx.x] = acc;
    __syncthreads();
    #pragma unroll
    for (int off = NTHREADS / 2; off > 0; off >>= 1) {
        if (threadIdx.x < off) red[threadIdx.x] += red[threadIdx.x + off];
        __syncthreads();
    }
    if (threadIdx.x == 0) out[0] = (float)(red[0] * inv_count);
}

extern "C" void kernel_launch(void* const* d_in, const int* in_sizes, int n_in,
                              void* d_out, int out_size, void* d_ws, size_t ws_size,
                              hipStream_t stream) {
    const float* img1 = (const float*)d_in[0];
    const float* img2 = (const float*)d_in[1];
    float* out = (float*)d_out;
    float* bsums = (float*)d_ws;

    // Gaussian weights, computed in double like the numpy reference, cast to f32.
    W11 wt;
    {
        double g[KS], sum = 0.0;
        for (int i = 0; i < KS; ++i) {
            const double x = (double)(i - KR);
            g[i] = exp(-(x * x) / (2.0 * 1.5 * 1.5));
            sum += g[i];
        }
        for (int i = 0; i < KS; ++i) wt.w[i] = (float)(g[i] / sum);
    }

    const int NC = 16 * 3;
    const dim3 grid(IMG_W / TW, IMG_H / TH, NC);           // 8 x 32 x 48 = 12288 blocks
    const int nblocks = grid.x * grid.y * grid.z;

    ssim_tile_kernel<<<grid, NTHREADS, 0, stream>>>(img1, img2, bsums, wt);

    const double inv_count = 1.0 / ((double)NC * IMG_H * IMG_W);
    ssim_reduce_kernel<<<1, NTHREADS, 0, stream>>>(bsums, nblocks, out, inv_count);
}

// Round 2
// 73.617 us; speedup vs baseline: 1.5705x; 1.5705x over previous
//
#include <hip/hip_runtime.h>
#include <math.h>

#define IMG_H 512
#define IMG_W 512
#define TW 256
#define TH 4
#define KR 5                 // radius
#define KS 11                // taps
#define SW (TW + 2 * KR)     // 266 staged columns
#define SWP 268              // padded stride (multiple of 4 -> 16B-aligned rows)
#define NTHREADS 256

struct W11 { float w[KS]; };

// Fused SSIM tile kernel: one 256x4 output tile of one (n,c) plane per block.
// Phase A: per-thread column strip vertical conv (global -> regs -> LDS).
// Phase B: horizontal conv from LDS (float4 reads) + SSIM map + reduce.
__global__ __launch_bounds__(NTHREADS)
void ssim_tile_kernel(const float* __restrict__ img1, const float* __restrict__ img2,
                      float* __restrict__ bsums, W11 wt) {
    __shared__ __align__(16) float s[5][TH][SWP];
    __shared__ float redw[4];

    const int col0  = blockIdx.x * TW;
    const int row0  = blockIdx.y * TH;
    const int plane = blockIdx.z;
    const float* __restrict__ p1 = img1 + (size_t)plane * (IMG_H * IMG_W);
    const float* __restrict__ p2 = img2 + (size_t)plane * (IMG_H * IMG_W);
    const int tid = threadIdx.x;

    const int  r0        = row0 - KR;
    const bool yinterior = (row0 >= KR) && (row0 + TH + KR <= IMG_H);

    // ---- Phase A: vertical 11-tap conv, per-thread column strip ----
    for (int c = tid; c < SW; c += NTHREADS) {
        const int  gc    = col0 - KR + c;
        const bool colok = (gc >= 0) && (gc < IMG_W);

        float acc[5][TH];
        #pragma unroll
        for (int f = 0; f < 5; ++f)
            #pragma unroll
            for (int r = 0; r < TH; ++r) acc[f][r] = 0.f;

        if (yinterior && colok) {
            const int off0 = r0 * IMG_W + gc;   // uniform base p1/p2 + varying 32b offset
            #pragma unroll
            for (int j = 0; j < TH + 2 * KR; ++j) {
                const float a = p1[off0 + j * IMG_W];
                const float b = p2[off0 + j * IMG_W];
                const float aa = a * a, bb = b * b, ab = a * b;
                #pragma unroll
                for (int r = 0; r < TH; ++r) {
                    const int k = j - r;            // compile-time after unroll
                    if (k >= 0 && k < KS) {
                        const float wk = wt.w[k];
                        acc[0][r] = fmaf(wk, a,  acc[0][r]);
                        acc[1][r] = fmaf(wk, b,  acc[1][r]);
                        acc[2][r] = fmaf(wk, aa, acc[2][r]);
                        acc[3][r] = fmaf(wk, bb, acc[3][r]);
                        acc[4][r] = fmaf(wk, ab, acc[4][r]);
                    }
                }
            }
        } else {
            #pragma unroll
            for (int j = 0; j < TH + 2 * KR; ++j) {
                const int  rr = r0 + j;
                const bool ok = colok && (rr >= 0) && (rr < IMG_H);
                const float a = ok ? p1[rr * IMG_W + gc] : 0.f;
                const float b = ok ? p2[rr * IMG_W + gc] : 0.f;
                const float aa = a * a, bb = b * b, ab = a * b;
                #pragma unroll
                for (int r = 0; r < TH; ++r) {
                    const int k = j - r;
                    if (k >= 0 && k < KS) {
                        const float wk = wt.w[k];
                        acc[0][r] = fmaf(wk, a,  acc[0][r]);
                        acc[1][r] = fmaf(wk, b,  acc[1][r]);
                        acc[2][r] = fmaf(wk, aa, acc[2][r]);
                        acc[3][r] = fmaf(wk, bb, acc[3][r]);
                        acc[4][r] = fmaf(wk, ab, acc[4][r]);
                    }
                }
            }
        }

        #pragma unroll
        for (int f = 0; f < 5; ++f)
            #pragma unroll
            for (int r = 0; r < TH; ++r) s[f][r][c] = acc[f][r];
    }
    __syncthreads();

    // ---- Phase B: horizontal 11-tap conv + SSIM map; 4 x-adjacent outputs/thread ----
    const float C1 = 0.0001f;   // 0.01^2
    const float C2 = 0.0009f;   // 0.03^2
    const int r  = tid >> 6;            // uniform within a wave
    const int c4 = (tid & 63) << 2;     // 16B-aligned staged col

    float conv[5][4];
    #pragma unroll
    for (int f = 0; f < 5; ++f) {
        const float4* rp = (const float4*)&s[f][r][c4];
        const float4 v0 = rp[0], v1 = rp[1], v2 = rp[2], v3 = rp[3];
        const float x[16] = {v0.x, v0.y, v0.z, v0.w,  v1.x, v1.y, v1.z, v1.w,
                             v2.x, v2.y, v2.z, v2.w,  v3.x, v3.y, v3.z, v3.w};
        #pragma unroll
        for (int j = 0; j < 4; ++j) {
            float m = wt.w[0] * x[j];
            #pragma unroll
            for (int k = 1; k < KS; ++k) m = fmaf(wt.w[k], x[j + k], m);
            conv[f][j] = m;
        }
    }

    float lsum = 0.f;
    #pragma unroll
    for (int j = 0; j < 4; ++j) {
        const float m1 = conv[0][j], m2 = conv[1][j];
        const float mu1_sq  = m1 * m1;
        const float mu2_sq  = m2 * m2;
        const float mu1_mu2 = m1 * m2;
        const float sig1  = conv[2][j] - mu1_sq;
        const float sig2  = conv[3][j] - mu2_sq;
        const float sig12 = conv[4][j] - mu1_mu2;
        const float num = fmaf(2.f, mu1_mu2, C1) * fmaf(2.f, sig12, C2);
        const float den = (mu1_sq + mu2_sq + C1) * (sig1 + sig2 + C2);
        lsum = fmaf(num, __builtin_amdgcn_rcpf(den), lsum);
    }

    // ---- reduce: wave shuffle, then 4 partials via LDS ----
    #pragma unroll
    for (int off = 32; off > 0; off >>= 1) lsum += __shfl_down(lsum, off);
    const int wid = tid >> 6;
    if ((tid & 63) == 0) redw[wid] = lsum;
    __syncthreads();
    if (tid == 0) {
        const int bid = (blockIdx.z * gridDim.y + blockIdx.y) * gridDim.x + blockIdx.x;
        bsums[bid] = redw[0] + redw[1] + redw[2] + redw[3];
    }
}

// Final reduce in double (fp32 sequential sum of the 1.26e7-magnitude total
// would exceed the 2.6e-4 threshold).
__global__ __launch_bounds__(NTHREADS)
void ssim_reduce_kernel(const float4* __restrict__ bsums, int n4,
                        float* __restrict__ out, double inv_count) {
    __shared__ double red[NTHREADS];
    double acc = 0.0;
    for (int i = threadIdx.x; i < n4; i += NTHREADS) {
        const float4 v = bsums[i];
        acc += (double)v.x + (double)v.y + (double)v.z + (double)v.w;
    }
    red[threadIdx.x] = acc;
    __syncthreads();
    #pragma unroll
    for (int off = NTHREADS / 2; off > 0; off >>= 1) {
        if (threadIdx.x < off) red[threadIdx.x] += red[threadIdx.x + off];
        __syncthreads();
    }
    if (threadIdx.x == 0) out[0] = (float)(red[0] * inv_count);
}

extern "C" void kernel_launch(void* const* d_in, const int* in_sizes, int n_in,
                              void* d_out, int out_size, void* d_ws, size_t ws_size,
                              hipStream_t stream) {
    const float* img1 = (const float*)d_in[0];
    const float* img2 = (const float*)d_in[1];
    float* out = (float*)d_out;
    float* bsums = (float*)d_ws;

    // Gaussian weights, computed in double like the numpy reference, cast to f32.
    W11 wt;
    {
        double g[KS], sum = 0.0;
        for (int i = 0; i < KS; ++i) {
            const double x = (double)(i - KR);
            g[i] = exp(-(x * x) / (2.0 * 1.5 * 1.5));
            sum += g[i];
        }
        for (int i = 0; i < KS; ++i) wt.w[i] = (float)(g[i] / sum);
    }

    const int NC = 16 * 3;
    const dim3 grid(IMG_W / TW, IMG_H / TH, NC);   // 2 x 128 x 48 = 12288 blocks
    const int nblocks = grid.x * grid.y * grid.z;

    ssim_tile_kernel<<<grid, NTHREADS, 0, stream>>>(img1, img2, bsums, wt);

    const double inv_count = 1.0 / ((double)NC * IMG_H * IMG_W);
    ssim_reduce_kernel<<<1, NTHREADS, 0, stream>>>((const float4*)bsums, nblocks / 4,
                                                   out, inv_count);
}

// Round 3
// 63.473 us; speedup vs baseline: 1.8214x; 1.1598x over previous
//
#include <hip/hip_runtime.h>
#include <math.h>

#define IMG_H 512
#define IMG_W 512
#define TW 256
#define TH 8
#define KR 5                 // radius
#define KS 11                // taps
#define SW (TW + 2 * KR)     // 266 staged columns
#define SWP 268              // padded row stride (multiple of 4 -> 16B aligned)
#define NTHREADS 512

struct W11 { float w[KS]; };

// Fused SSIM tile kernel: one 256x8 output tile of one (n,c) plane per block.
// Phase A: per-thread column-strip vertical conv (branchless clamped loads),
//          one strip per thread, single pass (no tail, no divergent dual path).
// Phase B: horizontal conv from LDS (float4 reads) + SSIM map + reduce.
__global__ __launch_bounds__(NTHREADS)
void ssim_tile_kernel(const float* __restrict__ img1, const float* __restrict__ img2,
                      float* __restrict__ bsums, W11 wt) {
    __shared__ __align__(16) float s[5][TH][SWP];
    __shared__ float redw[NTHREADS / 64];

    const int col0  = blockIdx.x * TW;
    const int row0  = blockIdx.y * TH;
    const int plane = blockIdx.z;
    const float* __restrict__ p1 = img1 + (size_t)plane * (IMG_H * IMG_W);
    const float* __restrict__ p2 = img2 + (size_t)plane * (IMG_H * IMG_W);
    const int tid = threadIdx.x;
    const int r0  = row0 - KR;

    // ---- Phase A: vertical 11-tap conv, one column strip per thread ----
    if (tid < SW) {
        const int  gc    = col0 - KR + tid;
        const int  gcc   = min(max(gc, 0), IMG_W - 1);          // per-lane clamp
        const bool colok = (gc >= 0) && (gc < IMG_W);

        float acc[5][TH];
        #pragma unroll
        for (int f = 0; f < 5; ++f)
            #pragma unroll
            for (int r = 0; r < TH; ++r) acc[f][r] = 0.f;

        #pragma unroll
        for (int j = 0; j < TH + 2 * KR; ++j) {
            const int  rr  = r0 + j;                            // block-uniform
            const int  rrc = min(max(rr, 0), IMG_H - 1);        // SALU clamp
            const bool ok  = colok && (rr >= 0) && (rr < IMG_H);
            float a = p1[rrc * IMG_W + gcc];
            float b = p2[rrc * IMG_W + gcc];
            a = ok ? a : 0.f;
            b = ok ? b : 0.f;
            const float aa = a * a, bb = b * b, ab = a * b;
            #pragma unroll
            for (int r = 0; r < TH; ++r) {
                const int k = j - r;                            // compile-time
                if (k >= 0 && k < KS) {
                    const float wk = wt.w[k];
                    acc[0][r] = fmaf(wk, a,  acc[0][r]);
                    acc[1][r] = fmaf(wk, b,  acc[1][r]);
                    acc[2][r] = fmaf(wk, aa, acc[2][r]);
                    acc[3][r] = fmaf(wk, bb, acc[3][r]);
                    acc[4][r] = fmaf(wk, ab, acc[4][r]);
                }
            }
        }

        #pragma unroll
        for (int f = 0; f < 5; ++f)
            #pragma unroll
            for (int r = 0; r < TH; ++r) s[f][r][tid] = acc[f][r];
    }
    __syncthreads();

    // ---- Phase B: horizontal 11-tap conv + SSIM map; 4 x-adjacent outputs/thread ----
    const float C1 = 0.0001f;   // 0.01^2
    const float C2 = 0.0009f;   // 0.03^2
    const int r  = tid >> 6;            // 8 rows, uniform within a wave
    const int c4 = (tid & 63) << 2;     // 16B-aligned staged col

    float conv[5][4];
    #pragma unroll
    for (int f = 0; f < 5; ++f) {
        const float4* rp = (const float4*)&s[f][r][c4];
        const float4 v0 = rp[0], v1 = rp[1], v2 = rp[2], v3 = rp[3];
        const float x[16] = {v0.x, v0.y, v0.z, v0.w,  v1.x, v1.y, v1.z, v1.w,
                             v2.x, v2.y, v2.z, v2.w,  v3.x, v3.y, v3.z, v3.w};
        #pragma unroll
        for (int j = 0; j < 4; ++j) {
            float m = wt.w[0] * x[j];
            #pragma unroll
            for (int k = 1; k < KS; ++k) m = fmaf(wt.w[k], x[j + k], m);
            conv[f][j] = m;
        }
    }

    float lsum = 0.f;
    #pragma unroll
    for (int j = 0; j < 4; ++j) {
        const float m1 = conv[0][j], m2 = conv[1][j];
        const float mu1_sq  = m1 * m1;
        const float mu2_sq  = m2 * m2;
        const float mu1_mu2 = m1 * m2;
        const float sig1  = conv[2][j] - mu1_sq;
        const float sig2  = conv[3][j] - mu2_sq;
        const float sig12 = conv[4][j] - mu1_mu2;
        const float num = fmaf(2.f, mu1_mu2, C1) * fmaf(2.f, sig12, C2);
        const float den = (mu1_sq + mu2_sq + C1) * (sig1 + sig2 + C2);
        lsum = fmaf(num, __builtin_amdgcn_rcpf(den), lsum);
    }

    // ---- reduce: wave shuffle, then per-wave partials via LDS ----
    #pragma unroll
    for (int off = 32; off > 0; off >>= 1) lsum += __shfl_down(lsum, off);
    const int wid = tid >> 6;
    if ((tid & 63) == 0) redw[wid] = lsum;
    __syncthreads();
    if (tid == 0) {
        float t = 0.f;
        #pragma unroll
        for (int w = 0; w < NTHREADS / 64; ++w) t += redw[w];
        const int bid = (blockIdx.z * gridDim.y + blockIdx.y) * gridDim.x + blockIdx.x;
        bsums[bid] = t;
    }
}

// Final reduce in double (fp32 sequential sum of the 1.26e7-magnitude total
// would exceed the 2.6e-4 threshold).
__global__ __launch_bounds__(256)
void ssim_reduce_kernel(const float4* __restrict__ bsums, int n4,
                        float* __restrict__ out, double inv_count) {
    __shared__ double red[256];
    double acc = 0.0;
    for (int i = threadIdx.x; i < n4; i += 256) {
        const float4 v = bsums[i];
        acc += (double)v.x + (double)v.y + (double)v.z + (double)v.w;
    }
    red[threadIdx.x] = acc;
    __syncthreads();
    #pragma unroll
    for (int off = 128; off > 0; off >>= 1) {
        if (threadIdx.x < off) red[threadIdx.x] += red[threadIdx.x + off];
        __syncthreads();
    }
    if (threadIdx.x == 0) out[0] = (float)(red[0] * inv_count);
}

extern "C" void kernel_launch(void* const* d_in, const int* in_sizes, int n_in,
                              void* d_out, int out_size, void* d_ws, size_t ws_size,
                              hipStream_t stream) {
    const float* img1 = (const float*)d_in[0];
    const float* img2 = (const float*)d_in[1];
    float* out = (float*)d_out;
    float* bsums = (float*)d_ws;

    // Gaussian weights, computed in double like the numpy reference, cast to f32.
    W11 wt;
    {
        double g[KS], sum = 0.0;
        for (int i = 0; i < KS; ++i) {
            const double x = (double)(i - KR);
            g[i] = exp(-(x * x) / (2.0 * 1.5 * 1.5));
            sum += g[i];
        }
        for (int i = 0; i < KS; ++i) wt.w[i] = (float)(g[i] / sum);
    }

    const int NC = 16 * 3;
    const dim3 grid(IMG_W / TW, IMG_H / TH, NC);   // 2 x 64 x 48 = 6144 blocks
    const int nblocks = grid.x * grid.y * grid.z;

    ssim_tile_kernel<<<grid, NTHREADS, 0, stream>>>(img1, img2, bsums, wt);

    const double inv_count = 1.0 / ((double)NC * IMG_H * IMG_W);
    ssim_reduce_kernel<<<1, 256, 0, stream>>>((const float4*)bsums, nblocks / 4,
                                              out, inv_count);
}

// Round 4
// 61.912 us; speedup vs baseline: 1.8674x; 1.0252x over previous
//
#include <hip/hip_runtime.h>
#include <math.h>

#define IMG_H 512
#define IMG_W 512
#define TH 4                 // output rows per block
#define KR 5                 // radius
#define KS 11                // taps
#define LW 524               // LDS row width: global cols -6..517 at idx col+6
#define NTHREADS 512

struct W11 { float w[KS]; };

// Fused SSIM band kernel: one 512x4 full-width output band per block.
// 4 staged fields (a, b, a^2+b^2, a*b) since the SSIM map only needs
// sigma1_sq + sigma2_sq as a sum.
// Phase A: vertical 11-tap conv, exactly one column per thread (no tail,
//          no column halo — halo cols of a zero-padded conv are zero).
// Phase B: horizontal 11-tap conv from LDS (4x float4/field) + map + reduce.
__global__ __launch_bounds__(NTHREADS)
void ssim_tile_kernel(const float* __restrict__ img1, const float* __restrict__ img2,
                      float* __restrict__ bsums, W11 wt) {
    __shared__ __align__(16) float s[4][TH][LW];   // 33,536 B -> 4 blocks/CU

    const int row0  = blockIdx.y * TH;
    const int plane = blockIdx.z;
    const float* __restrict__ p1 = img1 + (size_t)plane * (IMG_H * IMG_W);
    const float* __restrict__ p2 = img2 + (size_t)plane * (IMG_H * IMG_W);
    const int tid = threadIdx.x;
    const int r0  = row0 - KR;

    // Zero-fill the 12 alignment-halo columns (cols -6..-1, 512..517).
    if (tid < 12) {
        const int ci = (tid < 6) ? tid : (512 + tid);   // 0..5, 518..523
        #pragma unroll
        for (int f = 0; f < 4; ++f)
            #pragma unroll
            for (int r = 0; r < TH; ++r) s[f][r][ci] = 0.f;
    }

    // ---- Phase A: vertical conv, one column strip per thread ----
    float acc[4][TH];
    #pragma unroll
    for (int f = 0; f < 4; ++f)
        #pragma unroll
        for (int r = 0; r < TH; ++r) acc[f][r] = 0.f;

    const float* __restrict__ q1 = p1 + tid;
    const float* __restrict__ q2 = p2 + tid;
    #pragma unroll
    for (int j = 0; j < TH + 2 * KR; ++j) {         // 14 input rows
        const int rr = r0 + j;                      // block-uniform -> scalar branch
        float a = 0.f, b = 0.f;
        if (rr >= 0 && rr < IMG_H) {
            a = q1[rr * IMG_W];
            b = q2[rr * IMG_W];
        }
        const float ab = a * b;
        const float pp = fmaf(a, a, b * b);
        #pragma unroll
        for (int r = 0; r < TH; ++r) {
            const int k = j - r;                    // compile-time after unroll
            if (k >= 0 && k < KS) {
                const float wk = wt.w[k];
                acc[0][r] = fmaf(wk, a,  acc[0][r]);
                acc[1][r] = fmaf(wk, b,  acc[1][r]);
                acc[2][r] = fmaf(wk, pp, acc[2][r]);
                acc[3][r] = fmaf(wk, ab, acc[3][r]);
            }
        }
    }
    #pragma unroll
    for (int f = 0; f < 4; ++f)
        #pragma unroll
        for (int r = 0; r < TH; ++r) s[f][r][tid + 6] = acc[f][r];
    __syncthreads();

    // ---- Phase B: horizontal conv + SSIM map; 4 x-adjacent outputs/thread ----
    const float C1f = 0.0001f;   // 0.01^2
    const float C2f = 0.0009f;   // 0.03^2
    const int r  = tid >> 7;             // 4 rows x 128 threads
    const int c4 = (tid & 127) << 2;     // output col base, 16B-aligned idx

    float conv[4][4];
    #pragma unroll
    for (int f = 0; f < 4; ++f) {
        const float4* rp = (const float4*)&s[f][r][c4];   // idx c4 <-> col c4-6
        const float4 v0 = rp[0], v1 = rp[1], v2 = rp[2], v3 = rp[3];
        const float x[16] = {v0.x, v0.y, v0.z, v0.w,  v1.x, v1.y, v1.z, v1.w,
                             v2.x, v2.y, v2.z, v2.w,  v3.x, v3.y, v3.z, v3.w};
        // output col c4+j needs cols c4+j-5..c4+j+5 -> x[j+1 .. j+11]
        #pragma unroll
        for (int j = 0; j < 4; ++j) {
            float m = wt.w[0] * x[j + 1];
            #pragma unroll
            for (int k = 1; k < KS; ++k) m = fmaf(wt.w[k], x[j + 1 + k], m);
            conv[f][j] = m;
        }
    }

    float lsum = 0.f;
    #pragma unroll
    for (int j = 0; j < 4; ++j) {
        const float m1 = conv[0][j], m2 = conv[1][j];
        const float mpp = conv[2][j], m12 = conv[3][j];
        const float mu11 = m1 * m1;
        const float mu22 = m2 * m2;
        const float mu12 = m1 * m2;
        const float t     = mu11 + mu22;
        const float sigpp = mpp - t;          // sigma1_sq + sigma2_sq
        const float sig12 = m12 - mu12;
        const float num = fmaf(2.f, mu12, C1f) * fmaf(2.f, sig12, C2f);
        const float den = (t + C1f) * (sigpp + C2f);
        lsum = fmaf(num, __builtin_amdgcn_rcpf(den), lsum);
    }

    // ---- reduce: wave shuffle, then per-wave partials (reuse s after barrier) ----
    #pragma unroll
    for (int off = 32; off > 0; off >>= 1) lsum += __shfl_down(lsum, off);
    __syncthreads();                      // all LDS reads done; safe to reuse s
    if ((tid & 63) == 0) s[0][0][tid >> 6] = lsum;
    __syncthreads();
    if (tid == 0) {
        float t = 0.f;
        #pragma unroll
        for (int w = 0; w < NTHREADS / 64; ++w) t += s[0][0][w];
        const int bid = (blockIdx.z * gridDim.y + blockIdx.y) * gridDim.x + blockIdx.x;
        bsums[bid] = t;
    }
}

// Final reduce in double (fp32 sequential sum of the 1.26e7-magnitude total
// would exceed the 2.6e-4 threshold).
__global__ __launch_bounds__(256)
void ssim_reduce_kernel(const float4* __restrict__ bsums, int n4,
                        float* __restrict__ out, double inv_count) {
    __shared__ double red[256];
    double acc = 0.0;
    for (int i = threadIdx.x; i < n4; i += 256) {
        const float4 v = bsums[i];
        acc += (double)v.x + (double)v.y + (double)v.z + (double)v.w;
    }
    red[threadIdx.x] = acc;
    __syncthreads();
    #pragma unroll
    for (int off = 128; off > 0; off >>= 1) {
        if (threadIdx.x < off) red[threadIdx.x] += red[threadIdx.x + off];
        __syncthreads();
    }
    if (threadIdx.x == 0) out[0] = (float)(red[0] * inv_count);
}

extern "C" void kernel_launch(void* const* d_in, const int* in_sizes, int n_in,
                              void* d_out, int out_size, void* d_ws, size_t ws_size,
                              hipStream_t stream) {
    const float* img1 = (const float*)d_in[0];
    const float* img2 = (const float*)d_in[1];
    float* out = (float*)d_out;
    float* bsums = (float*)d_ws;

    // Gaussian weights, computed in double like the numpy reference, cast to f32.
    W11 wt;
    {
        double g[KS], sum = 0.0;
        for (int i = 0; i < KS; ++i) {
            const double x = (double)(i - KR);
            g[i] = exp(-(x * x) / (2.0 * 1.5 * 1.5));
            sum += g[i];
        }
        for (int i = 0; i < KS; ++i) wt.w[i] = (float)(g[i] / sum);
    }

    const int NC = 16 * 3;
    const dim3 grid(1, IMG_H / TH, NC);    // 1 x 128 x 48 = 6144 blocks
    const int nblocks = grid.x * grid.y * grid.z;

    ssim_tile_kernel<<<grid, NTHREADS, 0, stream>>>(img1, img2, bsums, wt);

    const double inv_count = 1.0 / ((double)NC * IMG_H * IMG_W);
    ssim_reduce_kernel<<<1, 256, 0, stream>>>((const float4*)bsums, nblocks / 4,
                                              out, inv_count);
}